// Round 14
// baseline (1873.605 us; speedup 1.0000x reference)
//
#include <hip/hip_runtime.h>

// ---------------------------------------------------------------------------
// STLT forward. bf16 activations+weights, MFMA GEMMs (16x16x32 bf16), f32
// accum/epilogues. Activations flat (65536, 256) rows = (b, i, j).
// T==S==64 => qt==qs, kt==ks: Weff = Wo[:, :256] + Wo[:, 256:].
// R14: resln family moves to 256-row tile (mfma_gemm_resln256: 8 waves,
// 32 MFMA/wave/K-step, 64KB dbuf, counted vmcnt(4)) -- mirrors the R13
// mfma_gemm256 win. FFN1 = gemm256, Qproj = 128^2 R9 kernel (unchanged).
// ---------------------------------------------------------------------------

typedef unsigned short u16;
typedef short s16;
typedef __attribute__((ext_vector_type(8))) s16 bfrag;   // 8 bf16 = 4 VGPR
typedef __attribute__((ext_vector_type(4))) float f32x4; // MFMA C/D

__device__ __forceinline__ float b2f(u16 u) {
  union { float f; unsigned int i; } v; v.i = ((unsigned int)u) << 16; return v.f;
}
__device__ __forceinline__ u16 f2b(float f) {
  union { float f; unsigned int i; } v; v.f = f;
  unsigned int x = v.i;
  return (u16)((x + 0x7FFFu + ((x >> 16) & 1u)) >> 16);
}
__device__ __forceinline__ float gelu_f(float v) {
  float u = 0.7978845608f * v * (1.0f + 0.044715f * v * v);
  float e = __expf(2.0f * u);
  return v * (1.0f - 1.0f / (e + 1.0f));
}

// async global->LDS, 16B per lane; LDS dest = base + lane*16 (wave-uniform base)
__device__ __forceinline__ void gload16(const void* g, void* l) {
  __builtin_amdgcn_global_load_lds(
      (const __attribute__((address_space(1))) unsigned int*)g,
      (__attribute__((address_space(3))) unsigned int*)l, 16, 0, 0);
}

__global__ void ws_signal(float* out, float v) { out[0] = v; }

// ---------------- batched weight conversion --------------------------------
__global__ void cvt_all(const float* s0, const float* s1, const float* s2,
                        const float* s3, const float* s4, const float* s5,
                        const float* s6,
                        u16* d0, u16* d1, u16* d2, u16* d3, u16* d4, u16* d5,
                        u16* d6,
                        int n0, int n1, int n2, int n3, int n4, int n5, int n6) {
  const float* S[7] = {s0, s1, s2, s3, s4, s5, s6};
  u16* D[7] = {d0, d1, d2, d3, d4, d5, d6};
  int N[7] = {n0, n1, n2, n3, n4, n5, n6};
  int j = blockIdx.y;
  int i = blockIdx.x * 256 + threadIdx.x;
  if (i < N[j]) D[j][i] = f2b(S[j][i]);
}

__global__ void weff_all(const float* s0, const float* s1, const float* s2,
                         const float* s3, const float* s4, const float* s5,
                         const float* s6,
                         u16* d0, u16* d1, u16* d2, u16* d3, u16* d4, u16* d5,
                         u16* d6) {
  const float* S[7] = {s0, s1, s2, s3, s4, s5, s6};
  u16* D[7] = {d0, d1, d2, d3, d4, d5, d6};
  int j = blockIdx.y;
  int n = blockIdx.x, k = threadIdx.x;
  D[j][n * 256 + k] = f2b(S[j][n * 512 + k] + S[j][n * 512 + 256 + k]);
}

// ---------------- positional encoding --------------------------------------
__global__ void pe_kernel(float* __restrict__ pe) {
  int l = blockIdx.x, d = threadIdx.x;
  int i = d >> 1;
  float div = expf((float)(2 * i) * (-9.210340371976184f / 256.0f));
  float ang = (float)l * div;
  pe[l * 256 + d] = (d & 1) ? cosf(ang) : sinf(ang);
}

// ---------------- embedding convs (circular, K=3), f32; enc+dec merged -----
__global__ void conv_sproj(const float* xe, const float* xd,
                           const float* we, const float* be,
                           const float* wd, const float* bd,
                           float* h1e, float* h1d) {
  int o = blockIdx.x, bb = blockIdx.y, l = threadIdx.x;  // l < 96
  int b = (bb < 16) ? bb : bb - 16;
  const float* x = (bb < 16) ? xe : xd;
  const float* w = (bb < 16) ? we : wd;
  const float* bi = (bb < 16) ? be : bd;
  float* h1 = (bb < 16) ? h1e : h1d;
  const float* wo = w + o * 192;
  const float* xb = x + (size_t)b * 96 * 64;
  float acc = bi[o];
#pragma unroll
  for (int k = 0; k < 3; ++k) {
    int lp = l + k - 1; if (lp < 0) lp += 96; if (lp >= 96) lp -= 96;
    const float* xr = xb + lp * 64;
    for (int c = 0; c < 64; ++c) acc = fmaf(xr[c], wo[c * 3 + k], acc);
  }
  h1[((size_t)b * 96 + o) * 96 + l] = acc;
}

__global__ void conv_scproj_t(const float* h1e, const float* h1d,
                              const float* we, const float* be,
                              const float* wd, const float* bd,
                              float* h2e, float* h2d) {
  int o = blockIdx.x, bb = blockIdx.y, l = threadIdx.x;  // o<64, l<96
  int b = (bb < 16) ? bb : bb - 16;
  const float* h1 = (bb < 16) ? h1e : h1d;
  const float* w = (bb < 16) ? we : wd;
  const float* bi = (bb < 16) ? be : bd;
  float* h2 = (bb < 16) ? h2e : h2d;
  const float* wo = w + o * 288;
  const float* hb = h1 + (size_t)b * 96 * 96;
  float acc = bi[o];
#pragma unroll
  for (int k = 0; k < 3; ++k) {
    int lp = l + k - 1; if (lp < 0) lp += 96; if (lp >= 96) lp -= 96;
    for (int c = 0; c < 96; ++c) acc = fmaf(hb[c * 96 + lp], wo[c * 3 + k], acc);
  }
  h2[((size_t)b * 64 + o) * 96 + l] = acc;
}

__global__ void conv_scproj_s(const float* h2e, const float* h2d,
                              const float* we, const float* be,
                              const float* wd, const float* bd,
                              float* h3e, float* h3d) {
  int o = blockIdx.x, bb = blockIdx.y, l = threadIdx.x;  // o<64, l<64
  int b = (bb < 16) ? bb : bb - 16;
  const float* h2 = (bb < 16) ? h2e : h2d;
  const float* w = (bb < 16) ? we : wd;
  const float* bi = (bb < 16) ? be : bd;
  float* h3 = (bb < 16) ? h3e : h3d;
  const float* wo = w + o * 288;
  const float* hb = h2 + (size_t)b * 64 * 96;
  float acc = bi[o];
#pragma unroll
  for (int k = 0; k < 3; ++k) {
    int lp = l + k - 1; if (lp < 0) lp += 64; if (lp >= 64) lp -= 64;
    for (int c = 0; c < 96; ++c) acc = fmaf(hb[lp * 96 + c], wo[c * 3 + k], acc);
  }
  h3[((size_t)b * 64 + o) * 64 + l] = acc;
}

__global__ void tok_embed(const float* h3e, const float* h3d,
                          const float* we, const float* be,
                          const float* wd, const float* bd,
                          const float* __restrict__ pe,
                          u16* Ee, u16* Ed) {
  int gg = blockIdx.x, d = threadIdx.x;   // gg < 2048
  int g = (gg < 1024) ? gg : gg - 1024;
  const float* h3 = (gg < 1024) ? h3e : h3d;
  const float* w = (gg < 1024) ? we : wd;
  const float* bi = (gg < 1024) ? be : bd;
  u16* E = (gg < 1024) ? Ee : Ed;
  __shared__ float row[64];
  if (d < 64) row[d] = h3[(size_t)g * 64 + d];
  __syncthreads();
  float w0 = w[d * 3], w1 = w[d * 3 + 1], w2 = w[d * 3 + 2], bd_ = bi[d];
  for (int j = 0; j < 64; ++j) {
    int jm = (j + 63) & 63, jp = (j + 1) & 63;
    float v = bd_ + row[jm] * w0 + row[j] * w1 + row[jp] * w2 + pe[j * 256 + d];
    E[((size_t)g * 64 + j) * 256 + d] = f2b(v);
  }
}

// ---------------- MFMA GEMM (R9: counted-vmcnt 2-phase, 128x128) -----------
template <int ACT, int NBX>
__global__ __launch_bounds__(256) void mfma_gemm(const u16* __restrict__ A,
                                                 const u16* __restrict__ W,
                                                 const float* __restrict__ bias,
                                                 u16* __restrict__ C, int N, int K,
                                                 int nby) {
  __shared__ s16 smem[16384];
  s16* A0 = smem;        s16* A1 = smem + 4096;
  s16* B0 = smem + 8192; s16* B1 = smem + 12288;
  constexpr int LB = (NBX == 8) ? 3 : 1;
  int f = blockIdx.x;
  int q = (NBX * nby) >> 3;
  int w = (f & 7) * q + (f >> 3);
  int bx = w & (NBX - 1), by = w >> LB;
  int t = threadIdx.x;
  int wave = t >> 6, lane = t & 63;
  int wr = wave >> 1, wc = wave & 1;
  int row0 = by * 128, col0 = bx * 128;
  int kc = (lane >> 4) & 3, rr = lane & 15;
  const u16* Ap0 = A + (size_t)(row0 + wave * 16 + rr) * K + kc * 8;
  const u16* Ap1 = A + (size_t)(row0 + (wave + 4) * 16 + rr) * K + kc * 8;
  const u16* Bp0 = W + (size_t)(col0 + wave * 16 + rr) * K + kc * 8;
  const u16* Bp1 = W + (size_t)(col0 + (wave + 4) * 16 + rr) * K + kc * 8;
  f32x4 acc[4][4];
#pragma unroll
  for (int m = 0; m < 4; ++m)
#pragma unroll
    for (int n = 0; n < 4; ++n) acc[m][n] = (f32x4){0.f, 0.f, 0.f, 0.f};

  auto STAGE = [&](s16* a, s16* b, int kidx) {
    int k0 = kidx * 32;
    gload16(Ap0 + k0, a + wave * 512);
    gload16(Ap1 + k0, a + (wave + 4) * 512);
    gload16(Bp0 + k0, b + wave * 512);
    gload16(Bp1 + k0, b + (wave + 4) * 512);
  };
  int nk = K >> 5;
  auto STEP = [&](const s16* a, const s16* b, s16* sa, s16* sb, int ks) {
    if (ks + 1 < nk) asm volatile("s_waitcnt vmcnt(4)" ::: "memory");
    else             asm volatile("s_waitcnt vmcnt(0)" ::: "memory");
    __builtin_amdgcn_sched_barrier(0);
    __builtin_amdgcn_s_barrier();
    __builtin_amdgcn_sched_barrier(0);
    bfrag af[4], bf[4];
#pragma unroll
    for (int m = 0; m < 4; ++m) af[m] = *(const bfrag*)(a + ((wr * 4 + m) * 64 + lane) * 8);
#pragma unroll
    for (int n = 0; n < 4; ++n) bf[n] = *(const bfrag*)(b + ((wc * 4 + n) * 64 + lane) * 8);
    asm volatile("s_waitcnt lgkmcnt(0)" ::: "memory");
    __builtin_amdgcn_sched_barrier(0);
    __builtin_amdgcn_s_barrier();
    __builtin_amdgcn_sched_barrier(0);
    if (ks + 2 < nk) STAGE(sa, sb, ks + 2);
#pragma unroll
    for (int m = 0; m < 4; ++m)
#pragma unroll
      for (int n = 0; n < 4; ++n)
        acc[m][n] = __builtin_amdgcn_mfma_f32_16x16x32_bf16(af[m], bf[n], acc[m][n], 0, 0, 0);
  };

  STAGE(A0, B0, 0);
  STAGE(A1, B1, 1);
  for (int ks = 0; ks < nk; ks += 2) {
    STEP(A0, B0, A0, B0, ks);
    STEP(A1, B1, A1, B1, ks + 1);
  }
  // ---- epilogue: LDS-staged coalesced stores ----
  s16* Cs = smem;
  int g4 = (lane >> 4) << 2;
  int cl = lane & 15;
  float bc[4];
#pragma unroll
  for (int n = 0; n < 4; ++n) bc[n] = bias[col0 + wc * 64 + n * 16 + cl];
#pragma unroll
  for (int P = 0; P < 4; ++P) {
    __syncthreads();
    if (wr == (P >> 1)) {
#pragma unroll
      for (int mm = 0; mm < 2; ++mm) {
        int m = (P & 1) * 2 + mm;
#pragma unroll
        for (int n = 0; n < 4; ++n) {
#pragma unroll
          for (int r = 0; r < 4; ++r) {
            float v = acc[m][n][r] + bc[n];
            if (ACT == 1) v = gelu_f(v);
            Cs[(mm * 16 + g4 + r) * 136 + wc * 64 + n * 16 + cl] = (s16)f2b(v);
          }
        }
      }
    }
    __syncthreads();
#pragma unroll
    for (int it = 0; it < 2; ++it) {
      int idx = it * 256 + t;
      int lr = idx >> 4, slot = idx & 15;
      *(uint4*)(C + (size_t)(row0 + P * 32 + lr) * N + col0 + slot * 8) =
          *(const uint4*)(Cs + lr * 136 + slot * 8);
    }
  }
}

// ---------------- MFMA GEMM 256x256 tile (FFN1): C = A@W^T + bias, GELU ----
template <int ACT>
__global__ __launch_bounds__(512) void mfma_gemm256(const u16* __restrict__ A,
                                                    const u16* __restrict__ W,
                                                    const float* __restrict__ bias,
                                                    u16* __restrict__ C, int N, int K,
                                                    int nby) {
  __shared__ s16 smem[32768];
  s16* A0 = smem;         s16* A1 = smem + 8192;
  s16* B0 = smem + 16384; s16* B1 = smem + 24576;
  int f = blockIdx.x;
  int q = (4 * nby) >> 3;
  int w = (f & 7) * q + (f >> 3);
  int bx = w & 3, by = w >> 2;
  int t = threadIdx.x;
  int wave = t >> 6, lane = t & 63;
  int wr = wave >> 2, wc = wave & 3;
  int row0 = by * 256, col0 = bx * 256;
  int kc = (lane >> 4) & 3, rr = lane & 15;
  const u16* Ap0 = A + (size_t)(row0 + wave * 16 + rr) * K + kc * 8;
  const u16* Ap1 = A + (size_t)(row0 + (wave + 8) * 16 + rr) * K + kc * 8;
  const u16* Bp0 = W + (size_t)(col0 + wave * 16 + rr) * K + kc * 8;
  const u16* Bp1 = W + (size_t)(col0 + (wave + 8) * 16 + rr) * K + kc * 8;
  f32x4 acc[8][4];
#pragma unroll
  for (int m = 0; m < 8; ++m)
#pragma unroll
    for (int n = 0; n < 4; ++n) acc[m][n] = (f32x4){0.f, 0.f, 0.f, 0.f};

  auto STAGE = [&](s16* a, s16* b, int kidx) {
    int k0 = kidx * 32;
    gload16(Ap0 + k0, a + wave * 512);
    gload16(Ap1 + k0, a + (wave + 8) * 512);
    gload16(Bp0 + k0, b + wave * 512);
    gload16(Bp1 + k0, b + (wave + 8) * 512);
  };
  int nk = K >> 5;
  auto STEP = [&](const s16* a, const s16* b, s16* sa, s16* sb, int ks) {
    if (ks + 1 < nk) asm volatile("s_waitcnt vmcnt(4)" ::: "memory");
    else             asm volatile("s_waitcnt vmcnt(0)" ::: "memory");
    __builtin_amdgcn_sched_barrier(0);
    __builtin_amdgcn_s_barrier();
    __builtin_amdgcn_sched_barrier(0);
    bfrag af[8], bf[4];
#pragma unroll
    for (int m = 0; m < 8; ++m) af[m] = *(const bfrag*)(a + ((wr * 8 + m) * 64 + lane) * 8);
#pragma unroll
    for (int n = 0; n < 4; ++n) bf[n] = *(const bfrag*)(b + ((wc * 4 + n) * 64 + lane) * 8);
    asm volatile("s_waitcnt lgkmcnt(0)" ::: "memory");
    __builtin_amdgcn_sched_barrier(0);
    __builtin_amdgcn_s_barrier();
    __builtin_amdgcn_sched_barrier(0);
    if (ks + 2 < nk) STAGE(sa, sb, ks + 2);
#pragma unroll
    for (int m = 0; m < 8; ++m)
#pragma unroll
      for (int n = 0; n < 4; ++n)
        acc[m][n] = __builtin_amdgcn_mfma_f32_16x16x32_bf16(af[m], bf[n], acc[m][n], 0, 0, 0);
  };

  STAGE(A0, B0, 0);
  STAGE(A1, B1, 1);
  for (int ks = 0; ks < nk; ks += 2) {
    STEP(A0, B0, A0, B0, ks);
    STEP(A1, B1, A1, B1, ks + 1);
  }
  // ---- epilogue: 8 passes of 32 rows x 256 cols, LDS-staged ----
  s16* Cs = smem;   // 32 x 264
  int g4 = (lane >> 4) << 2;
  int cl = lane & 15;
  float bc[4];
#pragma unroll
  for (int n = 0; n < 4; ++n) bc[n] = bias[col0 + wc * 64 + n * 16 + cl];
#pragma unroll
  for (int P = 0; P < 8; ++P) {
    __syncthreads();
    if (wr == (P >> 2)) {
#pragma unroll
      for (int mm = 0; mm < 2; ++mm) {
        int m = (P & 3) * 2 + mm;
#pragma unroll
        for (int n = 0; n < 4; ++n) {
#pragma unroll
          for (int r = 0; r < 4; ++r) {
            float v = acc[m][n][r] + bc[n];
            if (ACT == 1) v = gelu_f(v);
            Cs[(mm * 16 + g4 + r) * 264 + wc * 64 + n * 16 + cl] = (s16)f2b(v);
          }
        }
      }
    }
    __syncthreads();
#pragma unroll
    for (int it = 0; it < 2; ++it) {
      int idx = it * 512 + t;
      int lr = idx >> 5, slot = idx & 31;
      *(uint4*)(C + (size_t)(row0 + P * 32 + lr) * N + col0 + slot * 8) =
          *(const uint4*)(Cs + lr * 264 + slot * 8);
    }
  }
}

// ---------------- MFMA GEMM 256-row + bias + residual + LayerNorm ----------
// R(M,256) <- LN( X(M,K) @ W(256,K)^T + bias + R ). 256 rows/block, 512 thr,
// 8 waves (wr=wave>>2 over 2 row-halves of 128, wc=wave&3 over 4 col groups).
// 32 MFMA/wave/K-step, 64KB dbuf LDS, counted vmcnt(4). grid = M/256.
__global__ __launch_bounds__(512) void mfma_gemm_resln256(const u16* __restrict__ X,
                                                          const u16* __restrict__ W,
                                                          const float* __restrict__ bias,
                                                          u16* __restrict__ R,
                                                          const float* __restrict__ lnw,
                                                          const float* __restrict__ lnb,
                                                          int K) {
  __shared__ s16 smem[32768];
  __shared__ float pls[32][4][2];
  s16* A0 = smem;         s16* A1 = smem + 8192;
  s16* B0 = smem + 16384; s16* B1 = smem + 24576;
  int t = threadIdx.x;
  int wave = t >> 6, lane = t & 63;
  int wr = wave >> 2, wc = wave & 3;
  int row0 = blockIdx.x * 256;
  int kc = (lane >> 4) & 3, rr = lane & 15;
  const u16* Xp0 = X + (size_t)(row0 + wave * 16 + rr) * K + kc * 8;
  const u16* Xp1 = X + (size_t)(row0 + (wave + 8) * 16 + rr) * K + kc * 8;
  const u16* Wp0 = W + (size_t)(wave * 16 + rr) * K + kc * 8;
  const u16* Wp1 = W + (size_t)((wave + 8) * 16 + rr) * K + kc * 8;
  f32x4 acc[8][4];
#pragma unroll
  for (int m = 0; m < 8; ++m)
#pragma unroll
    for (int n = 0; n < 4; ++n) acc[m][n] = (f32x4){0.f, 0.f, 0.f, 0.f};

  auto STAGE = [&](s16* a, s16* b, int kidx) {
    int k0 = kidx * 32;
    gload16(Xp0 + k0, a + wave * 512);
    gload16(Xp1 + k0, a + (wave + 8) * 512);
    gload16(Wp0 + k0, b + wave * 512);
    gload16(Wp1 + k0, b + (wave + 8) * 512);
  };
  int nk = K >> 5;
  auto STEP = [&](const s16* a, const s16* b, s16* sa, s16* sb, int ks) {
    if (ks + 1 < nk) asm volatile("s_waitcnt vmcnt(4)" ::: "memory");
    else             asm volatile("s_waitcnt vmcnt(0)" ::: "memory");
    __builtin_amdgcn_sched_barrier(0);
    __builtin_amdgcn_s_barrier();
    __builtin_amdgcn_sched_barrier(0);
    bfrag af[8], bf[4];
#pragma unroll
    for (int m = 0; m < 8; ++m) af[m] = *(const bfrag*)(a + ((wr * 8 + m) * 64 + lane) * 8);
#pragma unroll
    for (int n = 0; n < 4; ++n) bf[n] = *(const bfrag*)(b + ((wc * 4 + n) * 64 + lane) * 8);
    asm volatile("s_waitcnt lgkmcnt(0)" ::: "memory");
    __builtin_amdgcn_sched_barrier(0);
    __builtin_amdgcn_s_barrier();
    __builtin_amdgcn_sched_barrier(0);
    if (ks + 2 < nk) STAGE(sa, sb, ks + 2);
#pragma unroll
    for (int m = 0; m < 8; ++m)
#pragma unroll
      for (int n = 0; n < 4; ++n)
        acc[m][n] = __builtin_amdgcn_mfma_f32_16x16x32_bf16(af[m], bf[n], acc[m][n], 0, 0, 0);
  };

  STAGE(A0, B0, 0);
  STAGE(A1, B1, 1);
  for (int ks = 0; ks < nk; ks += 2) {
    STEP(A0, B0, A0, B0, ks);
    STEP(A1, B1, A1, B1, ks + 1);
  }
  // ---- epilogue: 8 passes of 32 rows; residual + row LN ----
  s16* Rs = smem;        // 32 x 264 = 8448 <= 32768
  int g4 = (lane >> 4) << 2;
  int cl = lane & 15;
  float lw[4], lb[4], bc[4];
#pragma unroll
  for (int n = 0; n < 4; ++n) {
    int col = wc * 64 + n * 16 + cl;
    bc[n] = bias[col]; lw[n] = lnw[col]; lb[n] = lnb[col];
  }
#pragma unroll
  for (int P = 0; P < 8; ++P) {
    bool own = (wr == (P >> 2));
    __syncthreads();
#pragma unroll
    for (int it = 0; it < 2; ++it) {
      int idx = it * 512 + t;
      int lr = idx >> 5, slot = idx & 31;
      *(uint4*)(Rs + lr * 264 + slot * 8) =
          *(const uint4*)(R + (size_t)(row0 + P * 32 + lr) * 256 + slot * 8);
    }
    __syncthreads();
    if (own) {
#pragma unroll
      for (int mm = 0; mm < 2; ++mm) {
        int m = (P & 3) * 2 + mm;
#pragma unroll
        for (int r = 0; r < 4; ++r) {
          int lr = mm * 16 + g4 + r;
          float s = 0.f, s2 = 0.f;
#pragma unroll
          for (int n = 0; n < 4; ++n) {
            float v = acc[m][n][r] + bc[n] +
                      b2f((u16)Rs[lr * 264 + wc * 64 + n * 16 + cl]);
            acc[m][n][r] = v;
            s += v; s2 = fmaf(v, v, s2);
          }
#pragma unroll
          for (int o = 1; o < 16; o <<= 1) { s += __shfl_xor(s, o); s2 += __shfl_xor(s2, o); }
          if (cl == 0) { pls[lr][wc][0] = s; pls[lr][wc][1] = s2; }
        }
      }
    }
    __syncthreads();
    if (own) {
#pragma unroll
      for (int mm = 0; mm < 2; ++mm) {
        int m = (P & 3) * 2 + mm;
#pragma unroll
        for (int r = 0; r < 4; ++r) {
          int lr = mm * 16 + g4 + r;
          float s = pls[lr][0][0] + pls[lr][1][0] + pls[lr][2][0] + pls[lr][3][0];
          float s2 = pls[lr][0][1] + pls[lr][1][1] + pls[lr][2][1] + pls[lr][3][1];
          float mu = s * (1.0f / 256.0f);
          float var = fmaxf(s2 * (1.0f / 256.0f) - mu * mu, 0.0f);
          float rs = rsqrtf(var + 1e-5f);
#pragma unroll
          for (int n = 0; n < 4; ++n) {
            Rs[lr * 264 + wc * 64 + n * 16 + cl] =
                (s16)f2b((acc[m][n][r] - mu) * rs * lw[n] + lb[n]);
          }
        }
      }
    }
    __syncthreads();
#pragma unroll
    for (int it = 0; it < 2; ++it) {
      int idx = it * 512 + t;
      int lr = idx >> 5, slot = idx & 31;
      *(uint4*)(R + (size_t)(row0 + P * 32 + lr) * 256 + slot * 8) =
          *(const uint4*)(Rs + lr * 264 + slot * 8);
    }
  }
}

// ---------------- pooled linear attention (in-place on Q), LDS-staged ------
template <int CROSS, int CAUSAL>
__global__ __launch_bounds__(512) void lin_attn(u16* __restrict__ Q,
                                                const u16* __restrict__ KP) {
  __shared__ u16 qs[64 * 264];
  __shared__ float kpool[16][260];
  int p = blockIdx.x, t = threadIdx.x;
  u16* Qg = Q + (size_t)p * 16384;
#pragma unroll
  for (int i = 0; i < 4; ++i) {
    int idx = i * 512 + t;
    int row = idx >> 5, slot = idx & 31;
    *(uint4*)(qs + row * 264 + slot * 8) = *(const uint4*)(Qg + row * 256 + slot * 8);
  }
  __syncthreads();
  if (CROSS) {
    for (int idx = t; idx < 4096; idx += 512) {
      int s = idx >> 8, d = idx & 255;
      kpool[s][d] = b2f(KP[((size_t)p * 16 + s) * 256 + d]);
    }
  } else {
    for (int idx = t; idx < 4096; idx += 512) {
      int s = idx >> 8, d = idx & 255;
      const u16* b0 = qs + (4 * s) * 264 + d;
      kpool[s][d] = 0.25f * (b2f(b0[0]) + b2f(b0[264]) + b2f(b0[528]) + b2f(b0[792]));
    }
  }
  __syncthreads();
  int h = t >> 6, l = t & 63;
  u16* q = qs + l * 264 + h * 32;
  float qr[32];
#pragma unroll
  for (int e = 0; e < 32; e += 4) {
    ushort4 v = *(const ushort4*)&q[e];
    qr[e] = b2f(v.x); qr[e + 1] = b2f(v.y); qr[e + 2] = b2f(v.z); qr[e + 3] = b2f(v.w);
  }
  float sc[16], mx = -INFINITY;
#pragma unroll
  for (int s = 0; s < 16; ++s) {
    const float* kp = &kpool[s][h * 32];
    float d = 0.f;
#pragma unroll
    for (int e = 0; e < 32; ++e) d = fmaf(qr[e], kp[e], d);
    d *= 0.17677669529663687f;
    if (CAUSAL && s > l) d = -INFINITY;
    sc[s] = d; mx = fmaxf(mx, d);
  }
  float sum = 0.f;
#pragma unroll
  for (int s = 0; s < 16; ++s) { sc[s] = expf(sc[s] - mx); sum += sc[s]; }
  float inv = 1.0f / sum;
  float o[32] = {};
#pragma unroll
  for (int s = 0; s < 16; ++s) {
    float a = sc[s] * inv;
    const float* vp = &kpool[s][h * 32];
#pragma unroll
    for (int e = 0; e < 32; ++e) o[e] = fmaf(a, vp[e], o[e]);
  }
#pragma unroll
  for (int e = 0; e < 32; e += 4) {
    ushort4 v;
    v.x = f2b(o[e]); v.y = f2b(o[e + 1]); v.z = f2b(o[e + 2]); v.w = f2b(o[e + 3]);
    *(ushort4*)&q[e] = v;
  }
  __syncthreads();
#pragma unroll
  for (int i = 0; i < 4; ++i) {
    int idx = i * 512 + t;
    int row = idx >> 5, slot = idx & 31;
    *(uint4*)(Qg + row * 256 + slot * 8) = *(const uint4*)(qs + row * 264 + slot * 8);
  }
}

// ---------------- plain LayerNorm (in place), bf16 -------------------------
__global__ __launch_bounds__(256) void ln_bf(u16* __restrict__ X,
                                             const float* __restrict__ w,
                                             const float* __restrict__ b) {
  int lane = threadIdx.x & 63, wv = threadIdx.x >> 6;
  size_t row = (size_t)blockIdx.x * 4 + wv;
  size_t off = row * 256 + lane * 4;
  ushort4 xv = *(const ushort4*)(X + off);
  float v0 = b2f(xv.x), v1 = b2f(xv.y), v2 = b2f(xv.z), v3 = b2f(xv.w);
  float s = v0 + v1 + v2 + v3;
  float s2 = v0 * v0 + v1 * v1 + v2 * v2 + v3 * v3;
#pragma unroll
  for (int o = 32; o; o >>= 1) { s += __shfl_xor(s, o); s2 += __shfl_xor(s2, o); }
  float mu = s * (1.0f / 256.0f);
  float var = fmaxf(s2 * (1.0f / 256.0f) - mu * mu, 0.0f);
  float rs = rsqrtf(var + 1e-5f);
  float4 w4 = *(const float4*)(w + lane * 4);
  float4 b4 = *(const float4*)(b + lane * 4);
  ushort4 o4;
  o4.x = f2b((v0 - mu) * rs * w4.x + b4.x);
  o4.y = f2b((v1 - mu) * rs * w4.y + b4.y);
  o4.z = f2b((v2 - mu) * rs * w4.z + b4.z);
  o4.w = f2b((v3 - mu) * rs * w4.w + b4.w);
  *(ushort4*)(X + off) = o4;
}

// ---------------- pool over j (4:1) ----------------------------------------
__global__ void pool_bf(const u16* __restrict__ A, u16* __restrict__ P) {
  int r = blockIdx.x, d = threadIdx.x;
  int g = r >> 4, s = r & 15;
  const u16* src = A + ((size_t)g * 64 + 4 * (size_t)s) * 256 + d;
  float v = 0.25f * (b2f(src[0]) + b2f(src[256]) + b2f(src[512]) + b2f(src[768]));
  P[(size_t)r * 256 + d] = f2b(v);
}

// ---------------- mean over j + final projection + slice -------------------
__global__ __launch_bounds__(256) void mean_proj_bf(const u16* __restrict__ X,
                                                    const float* __restrict__ pw,
                                                    const float* __restrict__ pb,
                                                    float* __restrict__ out) {
  int bid = blockIdx.x;
  int b = bid >> 5, ii = bid & 31;
  int i = 32 + ii;
  __shared__ float md[256];
  int d = threadIdx.x;
  const u16* base = X + ((size_t)b * 64 + i) * 64 * 256 + d;
  float s = 0.f;
  for (int j = 0; j < 64; ++j) s += b2f(base[(size_t)j * 256]);
  md[d] = s * (1.0f / 64.0f);
  __syncthreads();
  if (d < 64) {
    float acc = pb[d];
    const float* wr = pw + d * 256;
    for (int k = 0; k < 256; ++k) acc = fmaf(md[k], wr[k], acc);
    out[((size_t)b * 32 + ii) * 64 + d] = acc;
  }
}

// ---------------------------------------------------------------------------
extern "C" void kernel_launch(void* const* d_in, const int* in_sizes, int n_in,
                              void* d_out, int out_size, void* d_ws, size_t ws_size,
                              hipStream_t stream) {
  (void)in_sizes; (void)out_size;
  if (n_in < 50) return;

  const float* x_enc = (const float*)d_in[0];
  const float* x_dec = (const float*)d_in[1];
  const float* enc_sproj_w = (const float*)d_in[2];
  const float* enc_sproj_b = (const float*)d_in[3];
  const float* enc_scproj_w = (const float*)d_in[4];
  const float* enc_scproj_b = (const float*)d_in[5];
  const float* enc_tok_w = (const float*)d_in[6];
  const float* enc_tok_b = (const float*)d_in[7];
  const float* dec_sproj_w = (const float*)d_in[8];
  const float* dec_sproj_b = (const float*)d_in[9];
  const float* dec_scproj_w = (const float*)d_in[10];
  const float* dec_scproj_b = (const float*)d_in[11];
  const float* dec_tok_w = (const float*)d_in[12];
  const float* dec_tok_b = (const float*)d_in[13];
  const float* e_Wq = (const float*)d_in[14];
  const float* e_bq = (const float*)d_in[15];
  const float* e_Wo = (const float*)d_in[16];
  const float* e_bo = (const float*)d_in[17];
  const float* e_c1w = (const float*)d_in[18];
  const float* e_c1b = (const float*)d_in[19];
  const float* e_c2w = (const float*)d_in[20];
  const float* e_c2b = (const float*)d_in[21];
  const float* e_ln1w = (const float*)d_in[22];
  const float* e_ln1b = (const float*)d_in[23];
  const float* e_ln2w = (const float*)d_in[24];
  const float* e_ln2b = (const float*)d_in[25];
  const float* enc_norm_w = (const float*)d_in[26];
  const float* enc_norm_b = (const float*)d_in[27];
  const float* d_sWq = (const float*)d_in[28];
  const float* d_sbq = (const float*)d_in[29];
  const float* d_sWo = (const float*)d_in[30];
  const float* d_sbo = (const float*)d_in[31];
  const float* d_cWq = (const float*)d_in[32];
  const float* d_cbq = (const float*)d_in[33];
  const float* d_cWo = (const float*)d_in[34];
  const float* d_cbo = (const float*)d_in[35];
  const float* d_c1w = (const float*)d_in[36];
  const float* d_c1b = (const float*)d_in[37];
  const float* d_c2w = (const float*)d_in[38];
  const float* d_c2b = (const float*)d_in[39];
  const float* d_ln1w = (const float*)d_in[40];
  const float* d_ln1b = (const float*)d_in[41];
  const float* d_ln2w = (const float*)d_in[42];
  const float* d_ln2b = (const float*)d_in[43];
  const float* d_ln3w = (const float*)d_in[44];
  const float* d_ln3b = (const float*)d_in[45];
  const float* dec_norm_w = (const float*)d_in[46];
  const float* dec_norm_b = (const float*)d_in[47];
  const float* proj_w = (const float*)d_in[48];
  const float* proj_b = (const float*)d_in[49];

  // ---- workspace layout ----
  const size_t ACT = 16777216;    // 65536*256
  const size_t POOLE = 4194304;   // 16384*256
  const size_t WBN = 3538944;     // bf16 weight pool elements
  size_t base_need = (3 * ACT + 2 * POOLE + WBN) * 2 +
                     (size_t)(16384 + 2 * (147456 + 98304 + 65536)) * 4;
  if (ws_size < base_need) {
    ws_signal<<<1, 1, 0, stream>>>((float*)d_out, (float)(ws_size >> 20));
    return;
  }
  char* wsb = (char*)d_ws;
  u16* A_enc = (u16*)wsb;  wsb += ACT * 2;
  u16* A_dec = (u16*)wsb;  wsb += ACT * 2;
  u16* T1 = (u16*)wsb;     wsb += ACT * 2;   // attn scratch
  u16* PA = (u16*)wsb;     wsb += POOLE * 2;
  u16* PK = (u16*)wsb;     wsb += POOLE * 2;
  u16* WB = (u16*)wsb;     wsb += WBN * 2;
  float* PE = (float*)wsb;  wsb += 16384 * 4;
  float* EH1 = (float*)wsb; wsb += 147456 * 4;
  float* EH2 = (float*)wsb; wsb += 98304 * 4;
  float* EH3 = (float*)wsb; wsb += 65536 * 4;
  float* FH1 = (float*)wsb; wsb += 147456 * 4;
  float* FH2 = (float*)wsb; wsb += 98304 * 4;
  float* FH3 = (float*)wsb; wsb += 65536 * 4;

  // adaptive FFN hidden buffer: prefer one full-width pass
  int hf_rows = 16384;
  u16* HF = T1;
  if (ws_size >= base_need + (size_t)65536 * 1024 * 2) {
    hf_rows = 65536; HF = (u16*)wsb;
  } else if (ws_size >= base_need + (size_t)32768 * 1024 * 2) {
    hf_rows = 32768; HF = (u16*)wsb;
  }

  // bf16 weight pool offsets (elements)
  u16* eWq = WB;                    // 3 x 65536
  u16* eWeff = WB + 196608;         // 3 x 65536
  u16* eC1 = WB + 393216;           // 3 x 262144
  u16* eC2 = WB + 1179648;          // 3 x 262144
  u16* dB = WB + 1966080;
  u16* dsWq = dB;                   // 2 x 65536
  u16* dsWeff = dB + 131072;        // 2 x 65536
  u16* dcWq = dB + 262144;          // 2 x 65536
  u16* dcWeff = dB + 393216;        // 2 x 65536
  u16* dC1 = dB + 524288;           // 2 x 262144
  u16* dC2 = dB + 1048576;          // 2 x 262144

  // ---- batched weight conversion (2 dispatches) ----
  cvt_all<<<dim3(3072, 7), 256, 0, stream>>>(
      e_Wq, e_c1w, e_c2w, d_sWq, d_cWq, d_c1w, d_c2w,
      eWq, eC1, eC2, dsWq, dcWq, dC1, dC2,
      196608, 786432, 786432, 131072, 131072, 524288, 524288);
  weff_all<<<dim3(256, 7), 256, 0, stream>>>(
      e_Wo, e_Wo + 131072, e_Wo + 262144, d_sWo, d_sWo + 131072,
      d_cWo, d_cWo + 131072,
      eWeff, eWeff + 65536, eWeff + 131072, dsWeff, dsWeff + 65536,
      dcWeff, dcWeff + 65536);

  pe_kernel<<<64, 256, 0, stream>>>(PE);

  // ---- embeddings (enc+dec merged) ----
  conv_sproj<<<dim3(96, 32), 96, 0, stream>>>(x_enc, x_dec, enc_sproj_w, enc_sproj_b,
                                              dec_sproj_w, dec_sproj_b, EH1, FH1);
  conv_scproj_t<<<dim3(64, 32), 96, 0, stream>>>(EH1, FH1, enc_scproj_w, enc_scproj_b,
                                                 dec_scproj_w, dec_scproj_b, EH2, FH2);
  conv_scproj_s<<<dim3(64, 32), 64, 0, stream>>>(EH2, FH2, enc_scproj_w, enc_scproj_b,
                                                 dec_scproj_w, dec_scproj_b, EH3, FH3);
  tok_embed<<<2048, 256, 0, stream>>>(EH3, FH3, enc_tok_w, enc_tok_b,
                                      dec_tok_w, dec_tok_b, PE, A_enc, A_dec);

  // ---- encoder layers ----
  for (int i = 0; i < 3; ++i) {
    mfma_gemm<0, 2><<<1024, 256, 0, stream>>>(A_enc, eWq + (size_t)i * 65536,
                                              e_bq + i * 256, T1, 256, 256, 512);
    lin_attn<0, 0><<<1024, 512, 0, stream>>>(T1, nullptr);
    mfma_gemm_resln256<<<256, 512, 0, stream>>>(T1, eWeff + (size_t)i * 65536, e_bo + i * 256,
                                                A_enc, e_ln1w + i * 256, e_ln1b + i * 256, 256);
    for (int m0 = 0; m0 < 65536; m0 += hf_rows) {
      u16* Xc = A_enc + (size_t)m0 * 256;
      int nby = hf_rows / 256;
      mfma_gemm256<1><<<4 * nby, 512, 0, stream>>>(
          Xc, eC1 + (size_t)i * 262144, e_c1b + i * 1024, HF, 1024, 256, nby);
      mfma_gemm_resln256<<<nby, 512, 0, stream>>>(
          HF, eC2 + (size_t)i * 262144, e_c2b + i * 256, Xc,
          e_ln2w + i * 256, e_ln2b + i * 256, 1024);
    }
  }
  ln_bf<<<16384, 256, 0, stream>>>(A_enc, enc_norm_w, enc_norm_b);
  pool_bf<<<16384, 256, 0, stream>>>(A_enc, PA);

  // ---- decoder layers ----
  for (int i = 0; i < 2; ++i) {
    mfma_gemm<0, 2><<<1024, 256, 0, stream>>>(A_dec, dsWq + (size_t)i * 65536,
                                              d_sbq + i * 256, T1, 256, 256, 512);
    lin_attn<0, 1><<<1024, 512, 0, stream>>>(T1, nullptr);
    mfma_gemm_resln256<<<256, 512, 0, stream>>>(T1, dsWeff + (size_t)i * 65536, d_sbo + i * 256,
                                                A_dec, d_ln1w + i * 256, d_ln1b + i * 256, 256);
    mfma_gemm<0, 2><<<1024, 256, 0, stream>>>(A_dec, dcWq + (size_t)i * 65536,
                                              d_cbq + i * 256, T1, 256, 256, 512);
    mfma_gemm<0, 2><<<256, 256, 0, stream>>>(PA, dcWq + (size_t)i * 65536,
                                             d_cbq + i * 256, PK, 256, 256, 128);
    lin_attn<1, 0><<<1024, 512, 0, stream>>>(T1, PK);
    mfma_gemm_resln256<<<256, 512, 0, stream>>>(T1, dcWeff + (size_t)i * 65536, d_cbo + i * 256,
                                                A_dec, d_ln2w + i * 256, d_ln2b + i * 256, 256);
    for (int m0 = 0; m0 < 65536; m0 += hf_rows) {
      u16* Xc = A_dec + (size_t)m0 * 256;
      int nby = hf_rows / 256;
      mfma_gemm256<1><<<4 * nby, 512, 0, stream>>>(
          Xc, dC1 + (size_t)i * 262144, d_c1b + i * 1024, HF, 1024, 256, nby);
      mfma_gemm_resln256<<<nby, 512, 0, stream>>>(
          HF, dC2 + (size_t)i * 262144, d_c2b + i * 256, Xc,
          d_ln3w + i * 256, d_ln3b + i * 256, 1024);
    }
  }
  ln_bf<<<16384, 256, 0, stream>>>(A_dec, dec_norm_w, dec_norm_b);

  mean_proj_bf<<<512, 256, 0, stream>>>(A_dec, proj_w, proj_b, (float*)d_out);
}

// Round 15
// 1725.324 us; speedup vs baseline: 1.0859x; 1.0859x over previous
//
#include <hip/hip_runtime.h>

// ---------------------------------------------------------------------------
// STLT forward. bf16 activations+weights, MFMA GEMMs (16x16x32 bf16), f32
// accum/epilogues. Activations flat (65536, 256) rows = (b, i, j).
// T==S==64 => qt==qs, kt==ks: Weff = Wo[:, :256] + Wo[:, 256:].
// R15: exact R13 structure (best, 1738us) + s_setprio(1/0) around MFMA
// clusters (T5). resln = 128-row R9 version (R14's 256-row resln regressed:
// grid 256 = 1 block/CU left no inter-block overlap).
// ---------------------------------------------------------------------------

typedef unsigned short u16;
typedef short s16;
typedef __attribute__((ext_vector_type(8))) s16 bfrag;   // 8 bf16 = 4 VGPR
typedef __attribute__((ext_vector_type(4))) float f32x4; // MFMA C/D

__device__ __forceinline__ float b2f(u16 u) {
  union { float f; unsigned int i; } v; v.i = ((unsigned int)u) << 16; return v.f;
}
__device__ __forceinline__ u16 f2b(float f) {
  union { float f; unsigned int i; } v; v.f = f;
  unsigned int x = v.i;
  return (u16)((x + 0x7FFFu + ((x >> 16) & 1u)) >> 16);
}
__device__ __forceinline__ float gelu_f(float v) {
  float u = 0.7978845608f * v * (1.0f + 0.044715f * v * v);
  float e = __expf(2.0f * u);
  return v * (1.0f - 1.0f / (e + 1.0f));
}

// async global->LDS, 16B per lane; LDS dest = base + lane*16 (wave-uniform base)
__device__ __forceinline__ void gload16(const void* g, void* l) {
  __builtin_amdgcn_global_load_lds(
      (const __attribute__((address_space(1))) unsigned int*)g,
      (__attribute__((address_space(3))) unsigned int*)l, 16, 0, 0);
}

__global__ void ws_signal(float* out, float v) { out[0] = v; }

// ---------------- batched weight conversion --------------------------------
__global__ void cvt_all(const float* s0, const float* s1, const float* s2,
                        const float* s3, const float* s4, const float* s5,
                        const float* s6,
                        u16* d0, u16* d1, u16* d2, u16* d3, u16* d4, u16* d5,
                        u16* d6,
                        int n0, int n1, int n2, int n3, int n4, int n5, int n6) {
  const float* S[7] = {s0, s1, s2, s3, s4, s5, s6};
  u16* D[7] = {d0, d1, d2, d3, d4, d5, d6};
  int N[7] = {n0, n1, n2, n3, n4, n5, n6};
  int j = blockIdx.y;
  int i = blockIdx.x * 256 + threadIdx.x;
  if (i < N[j]) D[j][i] = f2b(S[j][i]);
}

__global__ void weff_all(const float* s0, const float* s1, const float* s2,
                         const float* s3, const float* s4, const float* s5,
                         const float* s6,
                         u16* d0, u16* d1, u16* d2, u16* d3, u16* d4, u16* d5,
                         u16* d6) {
  const float* S[7] = {s0, s1, s2, s3, s4, s5, s6};
  u16* D[7] = {d0, d1, d2, d3, d4, d5, d6};
  int j = blockIdx.y;
  int n = blockIdx.x, k = threadIdx.x;
  D[j][n * 256 + k] = f2b(S[j][n * 512 + k] + S[j][n * 512 + 256 + k]);
}

// ---------------- positional encoding --------------------------------------
__global__ void pe_kernel(float* __restrict__ pe) {
  int l = blockIdx.x, d = threadIdx.x;
  int i = d >> 1;
  float div = expf((float)(2 * i) * (-9.210340371976184f / 256.0f));
  float ang = (float)l * div;
  pe[l * 256 + d] = (d & 1) ? cosf(ang) : sinf(ang);
}

// ---------------- embedding convs (circular, K=3), f32; enc+dec merged -----
__global__ void conv_sproj(const float* xe, const float* xd,
                           const float* we, const float* be,
                           const float* wd, const float* bd,
                           float* h1e, float* h1d) {
  int o = blockIdx.x, bb = blockIdx.y, l = threadIdx.x;  // l < 96
  int b = (bb < 16) ? bb : bb - 16;
  const float* x = (bb < 16) ? xe : xd;
  const float* w = (bb < 16) ? we : wd;
  const float* bi = (bb < 16) ? be : bd;
  float* h1 = (bb < 16) ? h1e : h1d;
  const float* wo = w + o * 192;
  const float* xb = x + (size_t)b * 96 * 64;
  float acc = bi[o];
#pragma unroll
  for (int k = 0; k < 3; ++k) {
    int lp = l + k - 1; if (lp < 0) lp += 96; if (lp >= 96) lp -= 96;
    const float* xr = xb + lp * 64;
    for (int c = 0; c < 64; ++c) acc = fmaf(xr[c], wo[c * 3 + k], acc);
  }
  h1[((size_t)b * 96 + o) * 96 + l] = acc;
}

__global__ void conv_scproj_t(const float* h1e, const float* h1d,
                              const float* we, const float* be,
                              const float* wd, const float* bd,
                              float* h2e, float* h2d) {
  int o = blockIdx.x, bb = blockIdx.y, l = threadIdx.x;  // o<64, l<96
  int b = (bb < 16) ? bb : bb - 16;
  const float* h1 = (bb < 16) ? h1e : h1d;
  const float* w = (bb < 16) ? we : wd;
  const float* bi = (bb < 16) ? be : bd;
  float* h2 = (bb < 16) ? h2e : h2d;
  const float* wo = w + o * 288;
  const float* hb = h1 + (size_t)b * 96 * 96;
  float acc = bi[o];
#pragma unroll
  for (int k = 0; k < 3; ++k) {
    int lp = l + k - 1; if (lp < 0) lp += 96; if (lp >= 96) lp -= 96;
    for (int c = 0; c < 96; ++c) acc = fmaf(hb[c * 96 + lp], wo[c * 3 + k], acc);
  }
  h2[((size_t)b * 64 + o) * 96 + l] = acc;
}

__global__ void conv_scproj_s(const float* h2e, const float* h2d,
                              const float* we, const float* be,
                              const float* wd, const float* bd,
                              float* h3e, float* h3d) {
  int o = blockIdx.x, bb = blockIdx.y, l = threadIdx.x;  // o<64, l<64
  int b = (bb < 16) ? bb : bb - 16;
  const float* h2 = (bb < 16) ? h2e : h2d;
  const float* w = (bb < 16) ? we : wd;
  const float* bi = (bb < 16) ? be : bd;
  float* h3 = (bb < 16) ? h3e : h3d;
  const float* wo = w + o * 288;
  const float* hb = h2 + (size_t)b * 64 * 96;
  float acc = bi[o];
#pragma unroll
  for (int k = 0; k < 3; ++k) {
    int lp = l + k - 1; if (lp < 0) lp += 64; if (lp >= 64) lp -= 64;
    for (int c = 0; c < 96; ++c) acc = fmaf(hb[lp * 96 + c], wo[c * 3 + k], acc);
  }
  h3[((size_t)b * 64 + o) * 64 + l] = acc;
}

__global__ void tok_embed(const float* h3e, const float* h3d,
                          const float* we, const float* be,
                          const float* wd, const float* bd,
                          const float* __restrict__ pe,
                          u16* Ee, u16* Ed) {
  int gg = blockIdx.x, d = threadIdx.x;   // gg < 2048
  int g = (gg < 1024) ? gg : gg - 1024;
  const float* h3 = (gg < 1024) ? h3e : h3d;
  const float* w = (gg < 1024) ? we : wd;
  const float* bi = (gg < 1024) ? be : bd;
  u16* E = (gg < 1024) ? Ee : Ed;
  __shared__ float row[64];
  if (d < 64) row[d] = h3[(size_t)g * 64 + d];
  __syncthreads();
  float w0 = w[d * 3], w1 = w[d * 3 + 1], w2 = w[d * 3 + 2], bd_ = bi[d];
  for (int j = 0; j < 64; ++j) {
    int jm = (j + 63) & 63, jp = (j + 1) & 63;
    float v = bd_ + row[jm] * w0 + row[j] * w1 + row[jp] * w2 + pe[j * 256 + d];
    E[((size_t)g * 64 + j) * 256 + d] = f2b(v);
  }
}

// ---------------- MFMA GEMM (counted-vmcnt 2-phase, 128x128) ---------------
template <int ACT, int NBX>
__global__ __launch_bounds__(256) void mfma_gemm(const u16* __restrict__ A,
                                                 const u16* __restrict__ W,
                                                 const float* __restrict__ bias,
                                                 u16* __restrict__ C, int N, int K,
                                                 int nby) {
  __shared__ s16 smem[16384];
  s16* A0 = smem;        s16* A1 = smem + 4096;
  s16* B0 = smem + 8192; s16* B1 = smem + 12288;
  constexpr int LB = (NBX == 8) ? 3 : 1;
  int f = blockIdx.x;
  int q = (NBX * nby) >> 3;
  int w = (f & 7) * q + (f >> 3);
  int bx = w & (NBX - 1), by = w >> LB;
  int t = threadIdx.x;
  int wave = t >> 6, lane = t & 63;
  int wr = wave >> 1, wc = wave & 1;
  int row0 = by * 128, col0 = bx * 128;
  int kc = (lane >> 4) & 3, rr = lane & 15;
  const u16* Ap0 = A + (size_t)(row0 + wave * 16 + rr) * K + kc * 8;
  const u16* Ap1 = A + (size_t)(row0 + (wave + 4) * 16 + rr) * K + kc * 8;
  const u16* Bp0 = W + (size_t)(col0 + wave * 16 + rr) * K + kc * 8;
  const u16* Bp1 = W + (size_t)(col0 + (wave + 4) * 16 + rr) * K + kc * 8;
  f32x4 acc[4][4];
#pragma unroll
  for (int m = 0; m < 4; ++m)
#pragma unroll
    for (int n = 0; n < 4; ++n) acc[m][n] = (f32x4){0.f, 0.f, 0.f, 0.f};

  auto STAGE = [&](s16* a, s16* b, int kidx) {
    int k0 = kidx * 32;
    gload16(Ap0 + k0, a + wave * 512);
    gload16(Ap1 + k0, a + (wave + 4) * 512);
    gload16(Bp0 + k0, b + wave * 512);
    gload16(Bp1 + k0, b + (wave + 4) * 512);
  };
  int nk = K >> 5;
  auto STEP = [&](const s16* a, const s16* b, s16* sa, s16* sb, int ks) {
    if (ks + 1 < nk) asm volatile("s_waitcnt vmcnt(4)" ::: "memory");
    else             asm volatile("s_waitcnt vmcnt(0)" ::: "memory");
    __builtin_amdgcn_sched_barrier(0);
    __builtin_amdgcn_s_barrier();
    __builtin_amdgcn_sched_barrier(0);
    bfrag af[4], bf[4];
#pragma unroll
    for (int m = 0; m < 4; ++m) af[m] = *(const bfrag*)(a + ((wr * 4 + m) * 64 + lane) * 8);
#pragma unroll
    for (int n = 0; n < 4; ++n) bf[n] = *(const bfrag*)(b + ((wc * 4 + n) * 64 + lane) * 8);
    asm volatile("s_waitcnt lgkmcnt(0)" ::: "memory");
    __builtin_amdgcn_sched_barrier(0);
    __builtin_amdgcn_s_barrier();
    __builtin_amdgcn_sched_barrier(0);
    if (ks + 2 < nk) STAGE(sa, sb, ks + 2);
    __builtin_amdgcn_s_setprio(1);
#pragma unroll
    for (int m = 0; m < 4; ++m)
#pragma unroll
      for (int n = 0; n < 4; ++n)
        acc[m][n] = __builtin_amdgcn_mfma_f32_16x16x32_bf16(af[m], bf[n], acc[m][n], 0, 0, 0);
    __builtin_amdgcn_s_setprio(0);
  };

  STAGE(A0, B0, 0);
  STAGE(A1, B1, 1);
  for (int ks = 0; ks < nk; ks += 2) {
    STEP(A0, B0, A0, B0, ks);
    STEP(A1, B1, A1, B1, ks + 1);
  }
  // ---- epilogue: LDS-staged coalesced stores ----
  s16* Cs = smem;
  int g4 = (lane >> 4) << 2;
  int cl = lane & 15;
  float bc[4];
#pragma unroll
  for (int n = 0; n < 4; ++n) bc[n] = bias[col0 + wc * 64 + n * 16 + cl];
#pragma unroll
  for (int P = 0; P < 4; ++P) {
    __syncthreads();
    if (wr == (P >> 1)) {
#pragma unroll
      for (int mm = 0; mm < 2; ++mm) {
        int m = (P & 1) * 2 + mm;
#pragma unroll
        for (int n = 0; n < 4; ++n) {
#pragma unroll
          for (int r = 0; r < 4; ++r) {
            float v = acc[m][n][r] + bc[n];
            if (ACT == 1) v = gelu_f(v);
            Cs[(mm * 16 + g4 + r) * 136 + wc * 64 + n * 16 + cl] = (s16)f2b(v);
          }
        }
      }
    }
    __syncthreads();
#pragma unroll
    for (int it = 0; it < 2; ++it) {
      int idx = it * 256 + t;
      int lr = idx >> 4, slot = idx & 15;
      *(uint4*)(C + (size_t)(row0 + P * 32 + lr) * N + col0 + slot * 8) =
          *(const uint4*)(Cs + lr * 136 + slot * 8);
    }
  }
}

// ---------------- MFMA GEMM 256x256 tile (FFN1): C = A@W^T + bias, GELU ----
template <int ACT>
__global__ __launch_bounds__(512) void mfma_gemm256(const u16* __restrict__ A,
                                                    const u16* __restrict__ W,
                                                    const float* __restrict__ bias,
                                                    u16* __restrict__ C, int N, int K,
                                                    int nby) {
  __shared__ s16 smem[32768];
  s16* A0 = smem;         s16* A1 = smem + 8192;
  s16* B0 = smem + 16384; s16* B1 = smem + 24576;
  int f = blockIdx.x;
  int q = (4 * nby) >> 3;
  int w = (f & 7) * q + (f >> 3);
  int bx = w & 3, by = w >> 2;
  int t = threadIdx.x;
  int wave = t >> 6, lane = t & 63;
  int wr = wave >> 2, wc = wave & 3;
  int row0 = by * 256, col0 = bx * 256;
  int kc = (lane >> 4) & 3, rr = lane & 15;
  const u16* Ap0 = A + (size_t)(row0 + wave * 16 + rr) * K + kc * 8;
  const u16* Ap1 = A + (size_t)(row0 + (wave + 8) * 16 + rr) * K + kc * 8;
  const u16* Bp0 = W + (size_t)(col0 + wave * 16 + rr) * K + kc * 8;
  const u16* Bp1 = W + (size_t)(col0 + (wave + 8) * 16 + rr) * K + kc * 8;
  f32x4 acc[8][4];
#pragma unroll
  for (int m = 0; m < 8; ++m)
#pragma unroll
    for (int n = 0; n < 4; ++n) acc[m][n] = (f32x4){0.f, 0.f, 0.f, 0.f};

  auto STAGE = [&](s16* a, s16* b, int kidx) {
    int k0 = kidx * 32;
    gload16(Ap0 + k0, a + wave * 512);
    gload16(Ap1 + k0, a + (wave + 8) * 512);
    gload16(Bp0 + k0, b + wave * 512);
    gload16(Bp1 + k0, b + (wave + 8) * 512);
  };
  int nk = K >> 5;
  auto STEP = [&](const s16* a, const s16* b, s16* sa, s16* sb, int ks) {
    if (ks + 1 < nk) asm volatile("s_waitcnt vmcnt(4)" ::: "memory");
    else             asm volatile("s_waitcnt vmcnt(0)" ::: "memory");
    __builtin_amdgcn_sched_barrier(0);
    __builtin_amdgcn_s_barrier();
    __builtin_amdgcn_sched_barrier(0);
    bfrag af[8], bf[4];
#pragma unroll
    for (int m = 0; m < 8; ++m) af[m] = *(const bfrag*)(a + ((wr * 8 + m) * 64 + lane) * 8);
#pragma unroll
    for (int n = 0; n < 4; ++n) bf[n] = *(const bfrag*)(b + ((wc * 4 + n) * 64 + lane) * 8);
    asm volatile("s_waitcnt lgkmcnt(0)" ::: "memory");
    __builtin_amdgcn_sched_barrier(0);
    __builtin_amdgcn_s_barrier();
    __builtin_amdgcn_sched_barrier(0);
    if (ks + 2 < nk) STAGE(sa, sb, ks + 2);
    __builtin_amdgcn_s_setprio(1);
#pragma unroll
    for (int m = 0; m < 8; ++m)
#pragma unroll
      for (int n = 0; n < 4; ++n)
        acc[m][n] = __builtin_amdgcn_mfma_f32_16x16x32_bf16(af[m], bf[n], acc[m][n], 0, 0, 0);
    __builtin_amdgcn_s_setprio(0);
  };

  STAGE(A0, B0, 0);
  STAGE(A1, B1, 1);
  for (int ks = 0; ks < nk; ks += 2) {
    STEP(A0, B0, A0, B0, ks);
    STEP(A1, B1, A1, B1, ks + 1);
  }
  // ---- epilogue: 8 passes of 32 rows x 256 cols, LDS-staged ----
  s16* Cs = smem;   // 32 x 264
  int g4 = (lane >> 4) << 2;
  int cl = lane & 15;
  float bc[4];
#pragma unroll
  for (int n = 0; n < 4; ++n) bc[n] = bias[col0 + wc * 64 + n * 16 + cl];
#pragma unroll
  for (int P = 0; P < 8; ++P) {
    __syncthreads();
    if (wr == (P >> 2)) {
#pragma unroll
      for (int mm = 0; mm < 2; ++mm) {
        int m = (P & 3) * 2 + mm;
#pragma unroll
        for (int n = 0; n < 4; ++n) {
#pragma unroll
          for (int r = 0; r < 4; ++r) {
            float v = acc[m][n][r] + bc[n];
            if (ACT == 1) v = gelu_f(v);
            Cs[(mm * 16 + g4 + r) * 264 + wc * 64 + n * 16 + cl] = (s16)f2b(v);
          }
        }
      }
    }
    __syncthreads();
#pragma unroll
    for (int it = 0; it < 2; ++it) {
      int idx = it * 512 + t;
      int lr = idx >> 5, slot = idx & 31;
      *(uint4*)(C + (size_t)(row0 + P * 32 + lr) * N + col0 + slot * 8) =
          *(const uint4*)(Cs + lr * 264 + slot * 8);
    }
  }
}

// ---------------- MFMA GEMM + bias + residual + LayerNorm (128-row) --------
__global__ __launch_bounds__(512) void mfma_gemm_resln(const u16* __restrict__ X,
                                                       const u16* __restrict__ W,
                                                       const float* __restrict__ bias,
                                                       u16* __restrict__ R,
                                                       const float* __restrict__ lnw,
                                                       const float* __restrict__ lnb,
                                                       int K) {
  __shared__ s16 smem[24576];
  __shared__ float pls[32][4][2];
  s16* A0 = smem;        s16* A1 = smem + 4096;
  s16* B0 = smem + 8192; s16* B1 = smem + 16384;
  int t = threadIdx.x;
  int wave = t >> 6, lane = t & 63;
  int wr = wave >> 2, wc = wave & 3;
  int row0 = blockIdx.x * 128;
  int kc = (lane >> 4) & 3, rr = lane & 15;
  const u16* Xp = X + (size_t)(row0 + wave * 16 + rr) * K + kc * 8;
  const u16* Wp0 = W + (size_t)(wave * 16 + rr) * K + kc * 8;
  const u16* Wp1 = W + (size_t)((wave + 8) * 16 + rr) * K + kc * 8;
  f32x4 acc[4][4];
#pragma unroll
  for (int m = 0; m < 4; ++m)
#pragma unroll
    for (int n = 0; n < 4; ++n) acc[m][n] = (f32x4){0.f, 0.f, 0.f, 0.f};

  auto STAGE = [&](s16* a, s16* b, int kidx) {
    int k0 = kidx * 32;
    gload16(Xp + k0, a + wave * 512);
    gload16(Wp0 + k0, b + wave * 512);
    gload16(Wp1 + k0, b + (wave + 8) * 512);
  };
  int nk = K >> 5;
  auto STEP = [&](const s16* a, const s16* b, s16* sa, s16* sb, int ks) {
    if (ks + 1 < nk) asm volatile("s_waitcnt vmcnt(3)" ::: "memory");
    else             asm volatile("s_waitcnt vmcnt(0)" ::: "memory");
    __builtin_amdgcn_sched_barrier(0);
    __builtin_amdgcn_s_barrier();
    __builtin_amdgcn_sched_barrier(0);
    bfrag af[4], bf[4];
#pragma unroll
    for (int m = 0; m < 4; ++m) af[m] = *(const bfrag*)(a + ((wr * 4 + m) * 64 + lane) * 8);
#pragma unroll
    for (int n = 0; n < 4; ++n) bf[n] = *(const bfrag*)(b + ((wc * 4 + n) * 64 + lane) * 8);
    asm volatile("s_waitcnt lgkmcnt(0)" ::: "memory");
    __builtin_amdgcn_sched_barrier(0);
    __builtin_amdgcn_s_barrier();
    __builtin_amdgcn_sched_barrier(0);
    if (ks + 2 < nk) STAGE(sa, sb, ks + 2);
    __builtin_amdgcn_s_setprio(1);
#pragma unroll
    for (int m = 0; m < 4; ++m)
#pragma unroll
      for (int n = 0; n < 4; ++n)
        acc[m][n] = __builtin_amdgcn_mfma_f32_16x16x32_bf16(af[m], bf[n], acc[m][n], 0, 0, 0);
    __builtin_amdgcn_s_setprio(0);
  };

  STAGE(A0, B0, 0);
  STAGE(A1, B1, 1);
  for (int ks = 0; ks < nk; ks += 2) {
    STEP(A0, B0, A0, B0, ks);
    STEP(A1, B1, A1, B1, ks + 1);
  }
  // ---- epilogue ----
  s16* Rs = smem;
  int g4 = (lane >> 4) << 2;
  int cl = lane & 15;
  float lw[4], lb[4], bc[4];
#pragma unroll
  for (int n = 0; n < 4; ++n) {
    int col = wc * 64 + n * 16 + cl;
    bc[n] = bias[col]; lw[n] = lnw[col]; lb[n] = lnb[col];
  }
#pragma unroll
  for (int P = 0; P < 4; ++P) {
    bool own = (wr == (P >> 1));
    __syncthreads();
#pragma unroll
    for (int it = 0; it < 2; ++it) {
      int idx = it * 512 + t;
      int lr = idx >> 5, slot = idx & 31;
      *(uint4*)(Rs + lr * 264 + slot * 8) =
          *(const uint4*)(R + (size_t)(row0 + P * 32 + lr) * 256 + slot * 8);
    }
    __syncthreads();
    if (own) {
#pragma unroll
      for (int mm = 0; mm < 2; ++mm) {
        int m = (P & 1) * 2 + mm;
#pragma unroll
        for (int r = 0; r < 4; ++r) {
          int lr = mm * 16 + g4 + r;
          float s = 0.f, s2 = 0.f;
#pragma unroll
          for (int n = 0; n < 4; ++n) {
            float v = acc[m][n][r] + bc[n] +
                      b2f((u16)Rs[lr * 264 + wc * 64 + n * 16 + cl]);
            acc[m][n][r] = v;
            s += v; s2 = fmaf(v, v, s2);
          }
#pragma unroll
          for (int o = 1; o < 16; o <<= 1) { s += __shfl_xor(s, o); s2 += __shfl_xor(s2, o); }
          if (cl == 0) { pls[lr][wc][0] = s; pls[lr][wc][1] = s2; }
        }
      }
    }
    __syncthreads();
    if (own) {
#pragma unroll
      for (int mm = 0; mm < 2; ++mm) {
        int m = (P & 1) * 2 + mm;
#pragma unroll
        for (int r = 0; r < 4; ++r) {
          int lr = mm * 16 + g4 + r;
          float s = pls[lr][0][0] + pls[lr][1][0] + pls[lr][2][0] + pls[lr][3][0];
          float s2 = pls[lr][0][1] + pls[lr][1][1] + pls[lr][2][1] + pls[lr][3][1];
          float mu = s * (1.0f / 256.0f);
          float var = fmaxf(s2 * (1.0f / 256.0f) - mu * mu, 0.0f);
          float rs = rsqrtf(var + 1e-5f);
#pragma unroll
          for (int n = 0; n < 4; ++n) {
            Rs[lr * 264 + wc * 64 + n * 16 + cl] =
                (s16)f2b((acc[m][n][r] - mu) * rs * lw[n] + lb[n]);
          }
        }
      }
    }
    __syncthreads();
#pragma unroll
    for (int it = 0; it < 2; ++it) {
      int idx = it * 512 + t;
      int lr = idx >> 5, slot = idx & 31;
      *(uint4*)(R + (size_t)(row0 + P * 32 + lr) * 256 + slot * 8) =
          *(const uint4*)(Rs + lr * 264 + slot * 8);
    }
  }
}

// ---------------- pooled linear attention (in-place on Q), LDS-staged ------
template <int CROSS, int CAUSAL>
__global__ __launch_bounds__(512) void lin_attn(u16* __restrict__ Q,
                                                const u16* __restrict__ KP) {
  __shared__ u16 qs[64 * 264];
  __shared__ float kpool[16][260];
  int p = blockIdx.x, t = threadIdx.x;
  u16* Qg = Q + (size_t)p * 16384;
#pragma unroll
  for (int i = 0; i < 4; ++i) {
    int idx = i * 512 + t;
    int row = idx >> 5, slot = idx & 31;
    *(uint4*)(qs + row * 264 + slot * 8) = *(const uint4*)(Qg + row * 256 + slot * 8);
  }
  __syncthreads();
  if (CROSS) {
    for (int idx = t; idx < 4096; idx += 512) {
      int s = idx >> 8, d = idx & 255;
      kpool[s][d] = b2f(KP[((size_t)p * 16 + s) * 256 + d]);
    }
  } else {
    for (int idx = t; idx < 4096; idx += 512) {
      int s = idx >> 8, d = idx & 255;
      const u16* b0 = qs + (4 * s) * 264 + d;
      kpool[s][d] = 0.25f * (b2f(b0[0]) + b2f(b0[264]) + b2f(b0[528]) + b2f(b0[792]));
    }
  }
  __syncthreads();
  int h = t >> 6, l = t & 63;
  u16* q = qs + l * 264 + h * 32;
  float qr[32];
#pragma unroll
  for (int e = 0; e < 32; e += 4) {
    ushort4 v = *(const ushort4*)&q[e];
    qr[e] = b2f(v.x); qr[e + 1] = b2f(v.y); qr[e + 2] = b2f(v.z); qr[e + 3] = b2f(v.w);
  }
  float sc[16], mx = -INFINITY;
#pragma unroll
  for (int s = 0; s < 16; ++s) {
    const float* kp = &kpool[s][h * 32];
    float d = 0.f;
#pragma unroll
    for (int e = 0; e < 32; ++e) d = fmaf(qr[e], kp[e], d);
    d *= 0.17677669529663687f;
    if (CAUSAL && s > l) d = -INFINITY;
    sc[s] = d; mx = fmaxf(mx, d);
  }
  float sum = 0.f;
#pragma unroll
  for (int s = 0; s < 16; ++s) { sc[s] = expf(sc[s] - mx); sum += sc[s]; }
  float inv = 1.0f / sum;
  float o[32] = {};
#pragma unroll
  for (int s = 0; s < 16; ++s) {
    float a = sc[s] * inv;
    const float* vp = &kpool[s][h * 32];
#pragma unroll
    for (int e = 0; e < 32; ++e) o[e] = fmaf(a, vp[e], o[e]);
  }
#pragma unroll
  for (int e = 0; e < 32; e += 4) {
    ushort4 v;
    v.x = f2b(o[e]); v.y = f2b(o[e + 1]); v.z = f2b(o[e + 2]); v.w = f2b(o[e + 3]);
    *(ushort4*)&q[e] = v;
  }
  __syncthreads();
#pragma unroll
  for (int i = 0; i < 4; ++i) {
    int idx = i * 512 + t;
    int row = idx >> 5, slot = idx & 31;
    *(uint4*)(Qg + row * 256 + slot * 8) = *(const uint4*)(qs + row * 264 + slot * 8);
  }
}

// ---------------- plain LayerNorm (in place), bf16 -------------------------
__global__ __launch_bounds__(256) void ln_bf(u16* __restrict__ X,
                                             const float* __restrict__ w,
                                             const float* __restrict__ b) {
  int lane = threadIdx.x & 63, wv = threadIdx.x >> 6;
  size_t row = (size_t)blockIdx.x * 4 + wv;
  size_t off = row * 256 + lane * 4;
  ushort4 xv = *(const ushort4*)(X + off);
  float v0 = b2f(xv.x), v1 = b2f(xv.y), v2 = b2f(xv.z), v3 = b2f(xv.w);
  float s = v0 + v1 + v2 + v3;
  float s2 = v0 * v0 + v1 * v1 + v2 * v2 + v3 * v3;
#pragma unroll
  for (int o = 32; o; o >>= 1) { s += __shfl_xor(s, o); s2 += __shfl_xor(s2, o); }
  float mu = s * (1.0f / 256.0f);
  float var = fmaxf(s2 * (1.0f / 256.0f) - mu * mu, 0.0f);
  float rs = rsqrtf(var + 1e-5f);
  float4 w4 = *(const float4*)(w + lane * 4);
  float4 b4 = *(const float4*)(b + lane * 4);
  ushort4 o4;
  o4.x = f2b((v0 - mu) * rs * w4.x + b4.x);
  o4.y = f2b((v1 - mu) * rs * w4.y + b4.y);
  o4.z = f2b((v2 - mu) * rs * w4.z + b4.z);
  o4.w = f2b((v3 - mu) * rs * w4.w + b4.w);
  *(ushort4*)(X + off) = o4;
}

// ---------------- pool over j (4:1) ----------------------------------------
__global__ void pool_bf(const u16* __restrict__ A, u16* __restrict__ P) {
  int r = blockIdx.x, d = threadIdx.x;
  int g = r >> 4, s = r & 15;
  const u16* src = A + ((size_t)g * 64 + 4 * (size_t)s) * 256 + d;
  float v = 0.25f * (b2f(src[0]) + b2f(src[256]) + b2f(src[512]) + b2f(src[768]));
  P[(size_t)r * 256 + d] = f2b(v);
}

// ---------------- mean over j + final projection + slice -------------------
__global__ __launch_bounds__(256) void mean_proj_bf(const u16* __restrict__ X,
                                                    const float* __restrict__ pw,
                                                    const float* __restrict__ pb,
                                                    float* __restrict__ out) {
  int bid = blockIdx.x;
  int b = bid >> 5, ii = bid & 31;
  int i = 32 + ii;
  __shared__ float md[256];
  int d = threadIdx.x;
  const u16* base = X + ((size_t)b * 64 + i) * 64 * 256 + d;
  float s = 0.f;
  for (int j = 0; j < 64; ++j) s += b2f(base[(size_t)j * 256]);
  md[d] = s * (1.0f / 64.0f);
  __syncthreads();
  if (d < 64) {
    float acc = pb[d];
    const float* wr = pw + d * 256;
    for (int k = 0; k < 256; ++k) acc = fmaf(md[k], wr[k], acc);
    out[((size_t)b * 32 + ii) * 64 + d] = acc;
  }
}

// ---------------------------------------------------------------------------
extern "C" void kernel_launch(void* const* d_in, const int* in_sizes, int n_in,
                              void* d_out, int out_size, void* d_ws, size_t ws_size,
                              hipStream_t stream) {
  (void)in_sizes; (void)out_size;
  if (n_in < 50) return;

  const float* x_enc = (const float*)d_in[0];
  const float* x_dec = (const float*)d_in[1];
  const float* enc_sproj_w = (const float*)d_in[2];
  const float* enc_sproj_b = (const float*)d_in[3];
  const float* enc_scproj_w = (const float*)d_in[4];
  const float* enc_scproj_b = (const float*)d_in[5];
  const float* enc_tok_w = (const float*)d_in[6];
  const float* enc_tok_b = (const float*)d_in[7];
  const float* dec_sproj_w = (const float*)d_in[8];
  const float* dec_sproj_b = (const float*)d_in[9];
  const float* dec_scproj_w = (const float*)d_in[10];
  const float* dec_scproj_b = (const float*)d_in[11];
  const float* dec_tok_w = (const float*)d_in[12];
  const float* dec_tok_b = (const float*)d_in[13];
  const float* e_Wq = (const float*)d_in[14];
  const float* e_bq = (const float*)d_in[15];
  const float* e_Wo = (const float*)d_in[16];
  const float* e_bo = (const float*)d_in[17];
  const float* e_c1w = (const float*)d_in[18];
  const float* e_c1b = (const float*)d_in[19];
  const float* e_c2w = (const float*)d_in[20];
  const float* e_c2b = (const float*)d_in[21];
  const float* e_ln1w = (const float*)d_in[22];
  const float* e_ln1b = (const float*)d_in[23];
  const float* e_ln2w = (const float*)d_in[24];
  const float* e_ln2b = (const float*)d_in[25];
  const float* enc_norm_w = (const float*)d_in[26];
  const float* enc_norm_b = (const float*)d_in[27];
  const float* d_sWq = (const float*)d_in[28];
  const float* d_sbq = (const float*)d_in[29];
  const float* d_sWo = (const float*)d_in[30];
  const float* d_sbo = (const float*)d_in[31];
  const float* d_cWq = (const float*)d_in[32];
  const float* d_cbq = (const float*)d_in[33];
  const float* d_cWo = (const float*)d_in[34];
  const float* d_cbo = (const float*)d_in[35];
  const float* d_c1w = (const float*)d_in[36];
  const float* d_c1b = (const float*)d_in[37];
  const float* d_c2w = (const float*)d_in[38];
  const float* d_c2b = (const float*)d_in[39];
  const float* d_ln1w = (const float*)d_in[40];
  const float* d_ln1b = (const float*)d_in[41];
  const float* d_ln2w = (const float*)d_in[42];
  const float* d_ln2b = (const float*)d_in[43];
  const float* d_ln3w = (const float*)d_in[44];
  const float* d_ln3b = (const float*)d_in[45];
  const float* dec_norm_w = (const float*)d_in[46];
  const float* dec_norm_b = (const float*)d_in[47];
  const float* proj_w = (const float*)d_in[48];
  const float* proj_b = (const float*)d_in[49];

  // ---- workspace layout ----
  const size_t ACT = 16777216;    // 65536*256
  const size_t POOLE = 4194304;   // 16384*256
  const size_t WBN = 3538944;     // bf16 weight pool elements
  size_t base_need = (3 * ACT + 2 * POOLE + WBN) * 2 +
                     (size_t)(16384 + 2 * (147456 + 98304 + 65536)) * 4;
  if (ws_size < base_need) {
    ws_signal<<<1, 1, 0, stream>>>((float*)d_out, (float)(ws_size >> 20));
    return;
  }
  char* wsb = (char*)d_ws;
  u16* A_enc = (u16*)wsb;  wsb += ACT * 2;
  u16* A_dec = (u16*)wsb;  wsb += ACT * 2;
  u16* T1 = (u16*)wsb;     wsb += ACT * 2;   // attn scratch
  u16* PA = (u16*)wsb;     wsb += POOLE * 2;
  u16* PK = (u16*)wsb;     wsb += POOLE * 2;
  u16* WB = (u16*)wsb;     wsb += WBN * 2;
  float* PE = (float*)wsb;  wsb += 16384 * 4;
  float* EH1 = (float*)wsb; wsb += 147456 * 4;
  float* EH2 = (float*)wsb; wsb += 98304 * 4;
  float* EH3 = (float*)wsb; wsb += 65536 * 4;
  float* FH1 = (float*)wsb; wsb += 147456 * 4;
  float* FH2 = (float*)wsb; wsb += 98304 * 4;
  float* FH3 = (float*)wsb; wsb += 65536 * 4;

  // adaptive FFN hidden buffer: prefer one full-width pass
  int hf_rows = 16384;
  u16* HF = T1;
  if (ws_size >= base_need + (size_t)65536 * 1024 * 2) {
    hf_rows = 65536; HF = (u16*)wsb;
  } else if (ws_size >= base_need + (size_t)32768 * 1024 * 2) {
    hf_rows = 32768; HF = (u16*)wsb;
  }

  // bf16 weight pool offsets (elements)
  u16* eWq = WB;                    // 3 x 65536
  u16* eWeff = WB + 196608;         // 3 x 65536
  u16* eC1 = WB + 393216;           // 3 x 262144
  u16* eC2 = WB + 1179648;          // 3 x 262144
  u16* dB = WB + 1966080;
  u16* dsWq = dB;                   // 2 x 65536
  u16* dsWeff = dB + 131072;        // 2 x 65536
  u16* dcWq = dB + 262144;          // 2 x 65536
  u16* dcWeff = dB + 393216;        // 2 x 65536
  u16* dC1 = dB + 524288;           // 2 x 262144
  u16* dC2 = dB + 1048576;          // 2 x 262144

  // ---- batched weight conversion (2 dispatches) ----
  cvt_all<<<dim3(3072, 7), 256, 0, stream>>>(
      e_Wq, e_c1w, e_c2w, d_sWq, d_cWq, d_c1w, d_c2w,
      eWq, eC1, eC2, dsWq, dcWq, dC1, dC2,
      196608, 786432, 786432, 131072, 131072, 524288, 524288);
  weff_all<<<dim3(256, 7), 256, 0, stream>>>(
      e_Wo, e_Wo + 131072, e_Wo + 262144, d_sWo, d_sWo + 131072,
      d_cWo, d_cWo + 131072,
      eWeff, eWeff + 65536, eWeff + 131072, dsWeff, dsWeff + 65536,
      dcWeff, dcWeff + 65536);

  pe_kernel<<<64, 256, 0, stream>>>(PE);

  // ---- embeddings (enc+dec merged) ----
  conv_sproj<<<dim3(96, 32), 96, 0, stream>>>(x_enc, x_dec, enc_sproj_w, enc_sproj_b,
                                              dec_sproj_w, dec_sproj_b, EH1, FH1);
  conv_scproj_t<<<dim3(64, 32), 96, 0, stream>>>(EH1, FH1, enc_scproj_w, enc_scproj_b,
                                                 dec_scproj_w, dec_scproj_b, EH2, FH2);
  conv_scproj_s<<<dim3(64, 32), 64, 0, stream>>>(EH2, FH2, enc_scproj_w, enc_scproj_b,
                                                 dec_scproj_w, dec_scproj_b, EH3, FH3);
  tok_embed<<<2048, 256, 0, stream>>>(EH3, FH3, enc_tok_w, enc_tok_b,
                                      dec_tok_w, dec_tok_b, PE, A_enc, A_dec);

  // ---- encoder layers ----
  for (int i = 0; i < 3; ++i) {
    mfma_gemm<0, 2><<<1024, 256, 0, stream>>>(A_enc, eWq + (size_t)i * 65536,
                                              e_bq + i * 256, T1, 256, 256, 512);
    lin_attn<0, 0><<<1024, 512, 0, stream>>>(T1, nullptr);
    mfma_gemm_resln<<<512, 512, 0, stream>>>(T1, eWeff + (size_t)i * 65536, e_bo + i * 256,
                                             A_enc, e_ln1w + i * 256, e_ln1b + i * 256, 256);
    for (int m0 = 0; m0 < 65536; m0 += hf_rows) {
      u16* Xc = A_enc + (size_t)m0 * 256;
      int nby = hf_rows / 256;
      mfma_gemm256<1><<<4 * nby, 512, 0, stream>>>(
          Xc, eC1 + (size_t)i * 262144, e_c1b + i * 1024, HF, 1024, 256, nby);
      mfma_gemm_resln<<<hf_rows / 128, 512, 0, stream>>>(
          HF, eC2 + (size_t)i * 262144, e_c2b + i * 256, Xc,
          e_ln2w + i * 256, e_ln2b + i * 256, 1024);
    }
  }
  ln_bf<<<16384, 256, 0, stream>>>(A_enc, enc_norm_w, enc_norm_b);
  pool_bf<<<16384, 256, 0, stream>>>(A_enc, PA);

  // ---- decoder layers ----
  for (int i = 0; i < 2; ++i) {
    mfma_gemm<0, 2><<<1024, 256, 0, stream>>>(A_dec, dsWq + (size_t)i * 65536,
                                              d_sbq + i * 256, T1, 256, 256, 512);
    lin_attn<0, 1><<<1024, 512, 0, stream>>>(T1, nullptr);
    mfma_gemm_resln<<<512, 512, 0, stream>>>(T1, dsWeff + (size_t)i * 65536, d_sbo + i * 256,
                                             A_dec, d_ln1w + i * 256, d_ln1b + i * 256, 256);
    mfma_gemm<0, 2><<<1024, 256, 0, stream>>>(A_dec, dcWq + (size_t)i * 65536,
                                              d_cbq + i * 256, T1, 256, 256, 512);
    mfma_gemm<0, 2><<<256, 256, 0, stream>>>(PA, dcWq + (size_t)i * 65536,
                                             d_cbq + i * 256, PK, 256, 256, 128);
    lin_attn<1, 0><<<1024, 512, 0, stream>>>(T1, PK);
    mfma_gemm_resln<<<512, 512, 0, stream>>>(T1, dcWeff + (size_t)i * 65536, d_cbo + i * 256,
                                             A_dec, d_ln2w + i * 256, d_ln2b + i * 256, 256);
    for (int m0 = 0; m0 < 65536; m0 += hf_rows) {
      u16* Xc = A_dec + (size_t)m0 * 256;
      int nby = hf_rows / 256;
      mfma_gemm256<1><<<4 * nby, 512, 0, stream>>>(
          Xc, dC1 + (size_t)i * 262144, d_c1b + i * 1024, HF, 1024, 256, nby);
      mfma_gemm_resln<<<hf_rows / 128, 512, 0, stream>>>(
          HF, dC2 + (size_t)i * 262144, d_c2b + i * 256, Xc,
          d_ln3w + i * 256, d_ln3b + i * 256, 1024);
    }
  }
  ln_bf<<<16384, 256, 0, stream>>>(A_dec, dec_norm_w, dec_norm_b);

  mean_proj_bf<<<512, 256, 0, stream>>>(A_dec, proj_w, proj_b, (float*)d_out);
}